// Round 1
// baseline (778.639 us; speedup 1.0000x reference)
//
#include <hip/hip_runtime.h>
#include <cmath>

#define HH 256
#define NB 32
#define LSEQ 50
#define BB 512
#define VOC 100000
#define VPAD 100032   // VOC rounded up to 64

typedef __attribute__((ext_vector_type(8))) short short8;
typedef __attribute__((ext_vector_type(4))) float f32x4;

static __device__ __forceinline__ unsigned short f2bf(float x) {
  unsigned u = __builtin_bit_cast(unsigned, x);
  u = (u + 0x7fff + ((u >> 16) & 1)) >> 16;   // round-to-nearest-even
  return (unsigned short)u;
}
static __device__ __forceinline__ float bf2f(unsigned short h) {
  unsigned u = ((unsigned)h) << 16;
  return __builtin_bit_cast(float, u);
}
static __device__ __forceinline__ uint2 pack_hi4(float4 x, uint2& pl) {
  const unsigned short h0 = f2bf(x.x), h1 = f2bf(x.y), h2 = f2bf(x.z), h3 = f2bf(x.w);
  const unsigned short l0 = f2bf(x.x - bf2f(h0)), l1 = f2bf(x.y - bf2f(h1));
  const unsigned short l2 = f2bf(x.z - bf2f(h2)), l3 = f2bf(x.w - bf2f(h3));
  uint2 ph;
  ph.x = (unsigned)h0 | ((unsigned)h1 << 16);
  ph.y = (unsigned)h2 | ((unsigned)h3 << 16);
  pl.x = (unsigned)l0 | ((unsigned)l1 << 16);
  pl.y = (unsigned)l2 | ((unsigned)l3 << 16);
  return ph;
}

// async global->LDS, 16B per lane; dest must be wave-uniform base + lane*16 (it is).
static __device__ __forceinline__ void cp16(void* lds, const void* g) {
  __builtin_amdgcn_global_load_lds(
      (const __attribute__((address_space(1))) unsigned int*)g,
      (__attribute__((address_space(3))) unsigned int*)lds, 16, 0, 0);
}

// ============ prep: transpose + bf16-split weights into ws ============
__global__ void prep_weights(const float* __restrict__ W_in, const float* __restrict__ b_in,
                             const float* __restrict__ W_out, const float* __restrict__ b_out,
                             const float* __restrict__ W_hh, const float* __restrict__ b_hh,
                             const float* __restrict__ W_ih, const float* __restrict__ fc2_w,
                             unsigned short* __restrict__ Wt_all, float* __restrict__ b_all,
                             unsigned short* __restrict__ WihT, unsigned short* __restrict__ fc2T)
{
  const int bid = blockIdx.x, k = threadIdx.x;
  if (bid < 1280) {
    const float* src; const float* bsrc; int col, nc;
    if (bid < 256)      { src = W_in;  bsrc = b_in;  col = bid;       nc = 256; }
    else if (bid < 512) { src = W_out; bsrc = b_out; col = bid - 256; nc = 256; }
    else                { src = W_hh;  bsrc = b_hh;  col = bid - 512; nc = 768; }
    Wt_all[bid * 256 + k] = f2bf(src[k * nc + col]);
    if (k == 0) b_all[bid] = bsrc[col];
  } else if (bid < 2048) {
    const int n = bid - 1280;
    WihT[n * 512 + k]       = f2bf(W_ih[k * 768 + n]);
    WihT[n * 512 + k + 256] = f2bf(W_ih[(k + 256) * 768 + n]);
  } else {
    const int n = bid - 2048;
    fc2T[n * 256 + k] = f2bf(fc2_w[k * 256 + n]);
  }
}

// ============ emb -> split bf16 hi/lo, rows 1..VOC, zero-padded to VPAD ============
__global__ __launch_bounds__(256) void embsplit(const float* __restrict__ emb,
                                                unsigned short* __restrict__ ehi,
                                                unsigned short* __restrict__ elo)
{
  const int idx4 = blockIdx.x * 256 + threadIdx.x;   // one float4 per thread
  const int v = idx4 >> 6, c4 = idx4 & 63;
  float4 x = make_float4(0.f, 0.f, 0.f, 0.f);
  if (v < VOC) x = *(const float4*)&emb[(size_t)(v + 1) * HH + c4 * 4];
  uint2 pl;
  const uint2 ph = pack_hi4(x, pl);
  *(uint2*)&ehi[(size_t)v * HH + c4 * 4] = ph;
  *(uint2*)&elo[(size_t)v * HH + c4 * 4] = pl;
}

// ============ A-split bf16 MFMA GEMM with global_load_lds staging ============
// 256 thr (4 waves 2x2), tile 128x128, BK=32.
__global__ __launch_bounds__(256, 3) void gemm_asplit_nt(
    const unsigned short* __restrict__ Ah, const unsigned short* __restrict__ Al,
    const unsigned short* __restrict__ Bt, const float* __restrict__ bias,
    float* __restrict__ C, int N, int K, int ldc)
{
  __shared__ unsigned short sAh[4 * 128 * 8];
  __shared__ unsigned short sAl[4 * 128 * 8];
  __shared__ unsigned short sB [4 * 128 * 8];
  const int tid = threadIdx.x;
  const int n0 = blockIdx.x * 128, m0 = blockIdx.y * 128;
  const int lane = tid & 63, wave = tid >> 6;
  const int quad = lane >> 4, l16 = lane & 15;
  const int wm = (wave >> 1) * 64, wn = (wave & 1) * 64;

  f32x4 acc[4][4];
#pragma unroll
  for (int i = 0; i < 4; ++i)
#pragma unroll
    for (int j = 0; j < 4; ++j)
#pragma unroll
      for (int r = 0; r < 4; ++r) acc[i][j][r] = 0.f;

  const int c0 = tid, c1 = tid + 256;          // chunk ids (512 chunks of 16B per tile)
  const int q0 = c0 >> 7, r0 = c0 & 127;
  const int q1c = c1 >> 7, r1 = c1 & 127;

  for (int k0 = 0; k0 < K; k0 += 32) {
    const size_t ga0 = (size_t)(m0 + r0) * K + k0 + q0 * 8;
    const size_t ga1 = (size_t)(m0 + r1) * K + k0 + q1c * 8;
    const size_t gb0 = (size_t)(n0 + r0) * K + k0 + q0 * 8;
    const size_t gb1 = (size_t)(n0 + r1) * K + k0 + q1c * 8;
    cp16(&sAh[c0 * 8], &Ah[ga0]);
    cp16(&sAh[c1 * 8], &Ah[ga1]);
    cp16(&sAl[c0 * 8], &Al[ga0]);
    cp16(&sAl[c1 * 8], &Al[ga1]);
    cp16(&sB [c0 * 8], &Bt[gb0]);
    cp16(&sB [c1 * 8], &Bt[gb1]);
    __syncthreads();

    short8 fah[4], fal[4];
#pragma unroll
    for (int ms = 0; ms < 4; ++ms) {
      const int row = wm + ms * 16 + l16;
      fah[ms] = *(const short8*)&sAh[(quad * 128 + row) * 8];
      fal[ms] = *(const short8*)&sAl[(quad * 128 + row) * 8];
    }
#pragma unroll
    for (int ns = 0; ns < 4; ++ns) {
      const int col = wn + ns * 16 + l16;
      const short8 fb = *(const short8*)&sB[(quad * 128 + col) * 8];
#pragma unroll
      for (int ms = 0; ms < 4; ++ms) {
        acc[ms][ns] = __builtin_amdgcn_mfma_f32_16x16x32_bf16(fah[ms], fb, acc[ms][ns], 0, 0, 0);
        acc[ms][ns] = __builtin_amdgcn_mfma_f32_16x16x32_bf16(fal[ms], fb, acc[ms][ns], 0, 0, 0);
      }
    }
    __syncthreads();
  }

#pragma unroll
  for (int ns = 0; ns < 4; ++ns) {
    const int n = n0 + wn + ns * 16 + l16;
    const float bv = bias[n];
#pragma unroll
    for (int ms = 0; ms < 4; ++ms) {
      const int mrow = m0 + wm + ms * 16 + quad * 4;
#pragma unroll
      for (int r = 0; r < 4; ++r)
        C[(size_t)(mrow + r) * ldc + n] = acc[ms][ns][r] + bv;
    }
  }
}

// ============ fp32 tiled GEMM kept for tiny q1 ============
#define TS 64
#define KSTEP 16
#define LDPF 68
__global__ __launch_bounds__(256) void gemm_nn_bias(
    const float* __restrict__ A, const float* __restrict__ W,
    const float* __restrict__ bias, float* __restrict__ C,
    int M, int N, int K)
{
  __shared__ float As[KSTEP * LDPF];
  __shared__ float Ws[KSTEP * LDPF];
  const int tid = threadIdx.x;
  const int tx = tid & 15, ty = tid >> 4;
  const int n0 = blockIdx.x * TS, m0 = blockIdx.y * TS;
  const int lkk = tid & 15, lm = tid >> 4;
  const int ln  = tid & 63, lkr = tid >> 6;
  float acc[4][4] = {};
  for (int k0 = 0; k0 < K; k0 += KSTEP) {
#pragma unroll
    for (int r = 0; r < 4; ++r)
      As[lkk * LDPF + lm + r * 16] = A[(m0 + lm + r * 16) * K + k0 + lkk];
#pragma unroll
    for (int r = 0; r < 4; ++r)
      Ws[(lkr + r * 4) * LDPF + ln] = W[(k0 + lkr + r * 4) * N + n0 + ln];
    __syncthreads();
#pragma unroll
    for (int kk = 0; kk < KSTEP; ++kk) {
      const float4 a4 = *(const float4*)(As + kk * LDPF + ty * 4);
      const float4 w4 = *(const float4*)(Ws + kk * LDPF + tx * 4);
      const float av[4] = {a4.x, a4.y, a4.z, a4.w};
      const float wv[4] = {w4.x, w4.y, w4.z, w4.w};
#pragma unroll
      for (int i = 0; i < 4; ++i)
#pragma unroll
        for (int j = 0; j < 4; ++j)
          acc[i][j] += av[i] * wv[j];
    }
    __syncthreads();
  }
  const float4 b4 = *(const float4*)(bias + n0 + tx * 4);
  const float bv[4] = {b4.x, b4.y, b4.z, b4.w};
#pragma unroll
  for (int i = 0; i < 4; ++i) {
    float4 o;
    o.x = acc[i][0] + bv[0]; o.y = acc[i][1] + bv[1];
    o.z = acc[i][2] + bv[2]; o.w = acc[i][3] + bv[3];
    *(float4*)(C + (m0 + ty * 4 + i) * N + n0 + tx * 4) = o;
  }
}

// ============ h0 = emb[items] (+ bf16 split) ============
__global__ void gather_h0(const int* __restrict__ items, const float* __restrict__ emb,
                          float* __restrict__ h0, unsigned short* __restrict__ h0h,
                          unsigned short* __restrict__ h0l, int total4)
{
  const int e = blockIdx.x * blockDim.x + threadIdx.x;
  if (e >= total4) return;
  const int row = e >> 6, c = e & 63;
  const int it = items[row];
  const float4 x = ((const float4*)emb)[it * 64 + c];
  ((float4*)h0)[e] = x;
  uint2 pl;
  const uint2 ph = pack_hi4(x, pl);
  *(uint2*)&h0h[e * 4] = ph;
  *(uint2*)&h0l[e * 4] = pl;
}

// ============ a_cat = [A_in@hin, A_out@hout] -> bf16 hi/lo ============
__global__ __launch_bounds__(256) void msg_kernel(
    const float* __restrict__ A, const float* __restrict__ C1,
    unsigned short* __restrict__ ach, unsigned short* __restrict__ acl)
{
  const int b = blockIdx.x;
  const int tid = threadIdx.x;
  __shared__ float Ash[NB * 64];
#pragma unroll
  for (int r = 0; r < 8; ++r)
    Ash[tid + r * 256] = A[b * (NB * 2 * NB) + tid + r * 256];
  float hi[NB], ho[NB];
#pragma unroll
  for (int j = 0; j < NB; ++j) {
    hi[j] = C1[(size_t)(b * NB + j) * 1280 + tid];
    ho[j] = C1[(size_t)(b * NB + j) * 1280 + 256 + tid];
  }
  __syncthreads();
  for (int i = 0; i < NB; ++i) {
    float si = 0.f, so = 0.f;
#pragma unroll
    for (int j = 0; j < NB; ++j) {
      si += Ash[i * 64 + j] * hi[j];
      so += Ash[i * 64 + 32 + j] * ho[j];
    }
    const int idx = (b * NB + i) * 512 + tid;
    const unsigned short sh = f2bf(si);
    ach[idx] = sh; acl[idx] = f2bf(si - bf2f(sh));
    const unsigned short oh = f2bf(so);
    ach[idx + 256] = oh; acl[idx + 256] = f2bf(so - bf2f(oh));
  }
}

// ============ GRU elementwise; h updated in place ============
__global__ void gru_kernel(const float* __restrict__ gi, const float* __restrict__ C1,
                           float* __restrict__ h, int total)
{
  const int idx = blockIdx.x * blockDim.x + threadIdx.x;
  if (idx >= total) return;
  const int row = idx >> 8, k = idx & 255;
  const float* gir = gi + (size_t)row * 768;
  const float* ghr = C1 + (size_t)row * 1280 + 512;
  const float ir = gir[k], iz = gir[k + 256], inn = gir[k + 512];
  const float hr = ghr[k], hz = ghr[k + 256], hn = ghr[k + 512];
  const float r = 1.f / (1.f + expf(-(ir + hr)));
  const float z = 1.f / (1.f + expf(-(iz + hz)));
  const float n = tanhf(inn + r * hn);
  const float h0v = h[idx];
  h[idx] = n + z * (h0v - n);
}

// ============ h_seqs gather (+ split) + tail; L split across gridDim.y ============
__global__ __launch_bounds__(256) void seq_gather2(
    const int* __restrict__ seq_alias, const int* __restrict__ mask,
    const float* __restrict__ h, float* __restrict__ h_seqs,
    unsigned short* __restrict__ hsh, unsigned short* __restrict__ hsl,
    float* __restrict__ h_tail)
{
  const int b = blockIdx.x, tid = threadIdx.x;
  __shared__ int tail_sh;
  if (tid < 64) {
    int s = (tid < LSEQ) ? mask[b * LSEQ + tid] : 0;
#pragma unroll
    for (int off = 32; off > 0; off >>= 1) s += __shfl_down(s, off, 64);
    if (tid == 0) tail_sh = s - 1;
  }
  __syncthreads();
  const int tail = tail_sh;
  const int l0 = blockIdx.y * 10;
  for (int l = l0; l < l0 + 10; ++l) {
    const int al = seq_alias[b * LSEQ + l];
    const float v = h[(size_t)(b * NB + al) * HH + tid];
    const int idx = (b * LSEQ + l) * HH + tid;
    h_seqs[idx] = v;
    const unsigned short vh = f2bf(v);
    hsh[idx] = vh; hsl[idx] = f2bf(v - bf2f(vh));
    if (l == tail) h_tail[b * HH + tid] = v;
  }
}

// ============ attention pooling: wave-parallel over L, one barrier ============
__global__ __launch_bounds__(256) void attn_kernel2(
    const float* __restrict__ q1, const float* __restrict__ q2,
    const float* __restrict__ fc3_w, const float* __restrict__ h_seqs,
    const int* __restrict__ mask, float* __restrict__ seq_emb)
{
  const int b = blockIdx.x;
  const int tid = threadIdx.x, wave = tid >> 6, lane = tid & 63;
  __shared__ float red[4 * HH];
  const float4 q1v = *(const float4*)&q1[b * HH + lane * 4];
  const float4 w3v = *(const float4*)&fc3_w[lane * 4];
  float4 acc = make_float4(0.f, 0.f, 0.f, 0.f);
  for (int l = wave; l < LSEQ; l += 4) {
    if (!mask[b * LSEQ + l]) continue;
    const float4 q2v = *(const float4*)&q2[(size_t)(b * LSEQ + l) * HH + lane * 4];
    float s = (1.f / (1.f + expf(-(q1v.x + q2v.x)))) * w3v.x
            + (1.f / (1.f + expf(-(q1v.y + q2v.y)))) * w3v.y
            + (1.f / (1.f + expf(-(q1v.z + q2v.z)))) * w3v.z
            + (1.f / (1.f + expf(-(q1v.w + q2v.w)))) * w3v.w;
#pragma unroll
    for (int off = 32; off > 0; off >>= 1) s += __shfl_xor(s, off, 64);
    const float4 hv = *(const float4*)&h_seqs[(size_t)(b * LSEQ + l) * HH + lane * 4];
    acc.x += s * hv.x; acc.y += s * hv.y; acc.z += s * hv.z; acc.w += s * hv.w;
  }
  *(float4*)&red[wave * HH + lane * 4] = acc;
  __syncthreads();
  const float r = red[tid] + red[HH + tid] + red[2 * HH + tid] + red[3 * HH + tid];
  seq_emb[b * HH + tid] = r;
}

// ============ split seq_emb ============
__global__ void split_seq(const float* __restrict__ s, unsigned short* __restrict__ hi,
                          unsigned short* __restrict__ lo, int n)
{
  const int i = blockIdx.x * blockDim.x + threadIdx.x;
  if (i >= n) return;
  const float x = s[i];
  const unsigned short h = f2bf(x);
  hi[i] = h;
  lo[i] = f2bf(x - bf2f(h));
}

// ============ scorer (pre-split path): no LDS, no barriers ============
// grid (2 m-blocks, 1563 v-blocks): m-pairs linear-adjacent -> shared L2 emb tile.
__global__ __launch_bounds__(256, 4) void scorer_presplit(
    const unsigned short* __restrict__ seq_hi,
    const unsigned short* __restrict__ seq_lo,
    const unsigned short* __restrict__ ehi,
    const unsigned short* __restrict__ elo,
    float* __restrict__ out)
{
  const int tid = threadIdx.x;
  const int m0 = blockIdx.x * 256;
  const int v0 = blockIdx.y * 64;
  const int lane = tid & 63, wave = tid >> 6;
  const int quad = lane >> 4, l16 = lane & 15;
  const int mwave = m0 + wave * 64;

  f32x4 acc[4][4];
#pragma unroll
  for (int i = 0; i < 4; ++i)
#pragma unroll
    for (int j = 0; j < 4; ++j)
#pragma unroll
      for (int r = 0; r < 4; ++r) acc[i][j][r] = 0.f;

#pragma unroll
  for (int ks = 0; ks < 8; ++ks) {
    const int kk = ks * 32 + quad * 8;
    short8 bh[4], bl[4];
#pragma unroll
    for (int vs = 0; vs < 4; ++vs) {
      const int boff = (v0 + vs * 16 + l16) * HH + kk;   // < 2^31
      bh[vs] = *(const short8*)&ehi[boff];
      bl[vs] = *(const short8*)&elo[boff];
    }
#pragma unroll
    for (int ms = 0; ms < 4; ++ms) {
      const int aoff = (mwave + ms * 16 + l16) * HH + kk;
      const short8 ah = *(const short8*)&seq_hi[aoff];
      const short8 al = *(const short8*)&seq_lo[aoff];
#pragma unroll
      for (int vs = 0; vs < 4; ++vs) {
        acc[ms][vs] = __builtin_amdgcn_mfma_f32_16x16x32_bf16(ah, bh[vs], acc[ms][vs], 0, 0, 0);
        acc[ms][vs] = __builtin_amdgcn_mfma_f32_16x16x32_bf16(ah, bl[vs], acc[ms][vs], 0, 0, 0);
        acc[ms][vs] = __builtin_amdgcn_mfma_f32_16x16x32_bf16(al, bh[vs], acc[ms][vs], 0, 0, 0);
      }
    }
  }

#pragma unroll
  for (int ms = 0; ms < 4; ++ms) {
    const int mrow = mwave + ms * 16 + quad * 4;
#pragma unroll
    for (int vs = 0; vs < 4; ++vs) {
      const int v = v0 + vs * 16 + l16;
      if (v < VOC) {
#pragma unroll
        for (int r = 0; r < 4; ++r)
          out[(size_t)(mrow + r) * VOC + v] = acc[ms][vs][r];
      }
    }
  }
}

// ============ scorer fallback (in-kernel conversion) — unchanged ============
#define ELD2 136
__global__ __launch_bounds__(256, 3) void scorer_mfma(
    const unsigned short* __restrict__ seq_hi,
    const unsigned short* __restrict__ seq_lo,
    const float* __restrict__ emb,
    float* __restrict__ out)
{
  __shared__ unsigned short ehi[64 * ELD2];
  __shared__ unsigned short elo[64 * ELD2];
  const int tid = threadIdx.x;
  const int v0 = blockIdx.x * 64;
  const int m0 = blockIdx.y * 256;
  const int lane = tid & 63, wave = tid >> 6;
  const int quad = lane >> 4, l16 = lane & 15;
  const int mwave = m0 + wave * 64;

  f32x4 acc[4][4];
#pragma unroll
  for (int i = 0; i < 4; ++i)
#pragma unroll
    for (int j = 0; j < 4; ++j)
#pragma unroll
      for (int r = 0; r < 4; ++r) acc[i][j][r] = 0.f;

  for (int p = 0; p < 2; ++p) {
#pragma unroll
    for (int i = 0; i < 8; ++i) {
      const int idx4 = tid + i * 256;
      const int row = idx4 >> 5, c4 = idx4 & 31;
      const int v = v0 + row;
      float4 x = make_float4(0.f, 0.f, 0.f, 0.f);
      if (v < VOC) x = *(const float4*)&emb[(size_t)(v + 1) * HH + p * 128 + c4 * 4];
      uint2 pl;
      const uint2 ph = pack_hi4(x, pl);
      *(uint2*)&ehi[row * ELD2 + c4 * 4] = ph;
      *(uint2*)&elo[row * ELD2 + c4 * 4] = pl;
    }
    __syncthreads();

#pragma unroll
    for (int ks = 0; ks < 4; ++ks) {
      const int kk = ks * 32;
      short8 bh[4], bl[4];
#pragma unroll
      for (int vs = 0; vs < 4; ++vs) {
        const int off = (vs * 16 + l16) * ELD2 + kk + quad * 8;
        bh[vs] = *(const short8*)&ehi[off];
        bl[vs] = *(const short8*)&elo[off];
      }
#pragma unroll
      for (int ms = 0; ms < 4; ++ms) {
        const int m = mwave + ms * 16 + l16;
        const int aoff = m * HH + p * 128 + kk + quad * 8;
        const short8 ah = *(const short8*)&seq_hi[aoff];
        const short8 al = *(const short8*)&seq_lo[aoff];
#pragma unroll
        for (int vs = 0; vs < 4; ++vs) {
          acc[ms][vs] = __builtin_amdgcn_mfma_f32_16x16x32_bf16(ah, bh[vs], acc[ms][vs], 0, 0, 0);
          acc[ms][vs] = __builtin_amdgcn_mfma_f32_16x16x32_bf16(ah, bl[vs], acc[ms][vs], 0, 0, 0);
          acc[ms][vs] = __builtin_amdgcn_mfma_f32_16x16x32_bf16(al, bh[vs], acc[ms][vs], 0, 0, 0);
        }
      }
    }
    __syncthreads();
  }

#pragma unroll
  for (int ms = 0; ms < 4; ++ms) {
    const int mrow = mwave + ms * 16 + quad * 4;
#pragma unroll
    for (int vs = 0; vs < 4; ++vs) {
      const int v = v0 + vs * 16 + l16;
      if (v < VOC) {
#pragma unroll
        for (int r = 0; r < 4; ++r)
          out[(size_t)(mrow + r) * VOC + v] = acc[ms][vs][r];
      }
    }
  }
}

extern "C" void kernel_launch(void* const* d_in, const int* in_sizes, int n_in,
                              void* d_out, int out_size, void* d_ws, size_t ws_size,
                              hipStream_t stream)
{
  const float* A      = (const float*)d_in[0];
  const int* items    = (const int*)d_in[1];
  const int* seq_al   = (const int*)d_in[2];
  const int* mask     = (const int*)d_in[3];
  const float* emb    = (const float*)d_in[4];
  const float* W_in   = (const float*)d_in[5];
  const float* b_in   = (const float*)d_in[6];
  const float* W_out  = (const float*)d_in[7];
  const float* b_out  = (const float*)d_in[8];
  const float* W_ih   = (const float*)d_in[9];
  const float* b_ih   = (const float*)d_in[10];
  const float* W_hh   = (const float*)d_in[11];
  const float* b_hh   = (const float*)d_in[12];
  const float* fc1_w  = (const float*)d_in[13];
  const float* fc1_b  = (const float*)d_in[14];
  const float* fc2_w  = (const float*)d_in[15];
  const float* fc2_b  = (const float*)d_in[16];
  const float* fc3_w  = (const float*)d_in[17];
  float* out = (float*)d_out;

  // ---- ws layout (floats) ----
  float* ws = (float*)d_ws;
  float* h0      = ws;                  // 4,194,304
  float* q1      = ws + 4194304;
  float* h_tail  = ws + 4325376;
  float* seq_emb = ws + 4456448;
  unsigned short* seq_hi = (unsigned short*)(ws + 4587520);
  unsigned short* seq_lo = (unsigned short*)(ws + 4653056);
  unsigned short* Wt_all = (unsigned short*)(ws + 4718592);
  unsigned short* WihT   = (unsigned short*)(ws + 4882432);
  unsigned short* fc2T   = (unsigned short*)(ws + 5079040);
  float* b_all   = ws + 5111808;        // 1,280
  // pre-split emb (VPAD x 256 us each) at 5,113,088 floats
  unsigned short* emb_hi = (unsigned short*)(ws + 5113088);
  unsigned short* emb_lo = (unsigned short*)(ws + 5113088 + (size_t)VPAD * HH / 2);
  const bool presplit = ws_size >= ((size_t)5113088 * 4 + (size_t)VPAD * HH * 4);

  // ---- d_out scratch ----
  float* C1 = out;
  unsigned short* acat_h = (unsigned short*)(out + 20971520);
  unsigned short* acat_l = (unsigned short*)(out + 25165824);
  float* gi = out + 29360128;
  unsigned short* h0h = (unsigned short*)(out + 41943040);
  unsigned short* h0l = (unsigned short*)(out + 44040192);
  float* h_seqs = out;
  unsigned short* hs_h = (unsigned short*)(out + 6553600);
  unsigned short* hs_l = (unsigned short*)(out + 9830400);
  float* q2 = out + 13107200;

  const int MR = BB * NB;  // 16384

  prep_weights<<<dim3(2304), dim3(256), 0, stream>>>(
      W_in, b_in, W_out, b_out, W_hh, b_hh, W_ih, fc2_w, Wt_all, b_all, WihT, fc2T);

  if (presplit)
    embsplit<<<dim3(VPAD * 64 / 256), dim3(256), 0, stream>>>(emb, emb_hi, emb_lo);

  gather_h0<<<dim3(MR * 64 / 256), dim3(256), 0, stream>>>(items, emb, h0, h0h, h0l, MR * 64);

  gemm_asplit_nt<<<dim3(1280 / 128, MR / 128), dim3(256), 0, stream>>>(
      h0h, h0l, Wt_all, b_all, C1, 1280, 256, 1280);

  msg_kernel<<<dim3(BB), dim3(256), 0, stream>>>(A, C1, acat_h, acat_l);

  gemm_asplit_nt<<<dim3(768 / 128, MR / 128), dim3(256), 0, stream>>>(
      acat_h, acat_l, WihT, b_ih, gi, 768, 512, 768);

  gru_kernel<<<dim3(MR * HH / 256), dim3(256), 0, stream>>>(gi, C1, h0, MR * HH);

  seq_gather2<<<dim3(BB, 5), dim3(256), 0, stream>>>(seq_al, mask, h0, h_seqs, hs_h, hs_l, h_tail);

  gemm_asplit_nt<<<dim3(256 / 128, (BB * LSEQ) / 128), dim3(256), 0, stream>>>(
      hs_h, hs_l, fc2T, fc2_b, q2, 256, 256, 256);

  gemm_nn_bias<<<dim3(HH / TS, BB / TS), dim3(256), 0, stream>>>(h_tail, fc1_w, fc1_b, q1, BB, HH, HH);

  attn_kernel2<<<dim3(BB), dim3(256), 0, stream>>>(q1, q2, fc3_w, h_seqs, mask, seq_emb);

  split_seq<<<dim3(BB * HH / 256), dim3(256), 0, stream>>>(seq_emb, seq_hi, seq_lo, BB * HH);

  if (presplit)
    scorer_presplit<<<dim3(2, (VOC + 63) / 64), dim3(256), 0, stream>>>(
        seq_hi, seq_lo, emb_hi, emb_lo, out);
  else
    scorer_mfma<<<dim3((VOC + 63) / 64, 2), dim3(256), 0, stream>>>(seq_hi, seq_lo, emb, out);
}

// Round 2
// 685.021 us; speedup vs baseline: 1.1367x; 1.1367x over previous
//
#include <hip/hip_runtime.h>
#include <cmath>

#define HH 256
#define NB 32
#define LSEQ 50
#define BB 512
#define VOC 100000
#define VPAD 100032   // VOC rounded up to 64
#define NTILE (VPAD / 64)   // 1563 v-tiles

typedef __attribute__((ext_vector_type(8))) short short8;
typedef __attribute__((ext_vector_type(4))) float f32x4;

static __device__ __forceinline__ unsigned short f2bf(float x) {
  unsigned u = __builtin_bit_cast(unsigned, x);
  u = (u + 0x7fff + ((u >> 16) & 1)) >> 16;   // round-to-nearest-even
  return (unsigned short)u;
}
static __device__ __forceinline__ float bf2f(unsigned short h) {
  unsigned u = ((unsigned)h) << 16;
  return __builtin_bit_cast(float, u);
}
static __device__ __forceinline__ uint2 pack_hi4(float4 x, uint2& pl) {
  const unsigned short h0 = f2bf(x.x), h1 = f2bf(x.y), h2 = f2bf(x.z), h3 = f2bf(x.w);
  const unsigned short l0 = f2bf(x.x - bf2f(h0)), l1 = f2bf(x.y - bf2f(h1));
  const unsigned short l2 = f2bf(x.z - bf2f(h2)), l3 = f2bf(x.w - bf2f(h3));
  uint2 ph;
  ph.x = (unsigned)h0 | ((unsigned)h1 << 16);
  ph.y = (unsigned)h2 | ((unsigned)h3 << 16);
  pl.x = (unsigned)l0 | ((unsigned)l1 << 16);
  pl.y = (unsigned)l2 | ((unsigned)l3 << 16);
  return ph;
}

// async global->LDS, 16B per lane; dest must be wave-uniform base + lane*16 (it is).
static __device__ __forceinline__ void cp16(void* lds, const void* g) {
  __builtin_amdgcn_global_load_lds(
      (const __attribute__((address_space(1))) unsigned int*)g,
      (__attribute__((address_space(3))) unsigned int*)lds, 16, 0, 0);
}

// ============ prep: transpose + bf16-split weights into ws ============
__global__ void prep_weights(const float* __restrict__ W_in, const float* __restrict__ b_in,
                             const float* __restrict__ W_out, const float* __restrict__ b_out,
                             const float* __restrict__ W_hh, const float* __restrict__ b_hh,
                             const float* __restrict__ W_ih, const float* __restrict__ fc2_w,
                             unsigned short* __restrict__ Wt_all, float* __restrict__ b_all,
                             unsigned short* __restrict__ WihT, unsigned short* __restrict__ fc2T)
{
  const int bid = blockIdx.x, k = threadIdx.x;
  if (bid < 1280) {
    const float* src; const float* bsrc; int col, nc;
    if (bid < 256)      { src = W_in;  bsrc = b_in;  col = bid;       nc = 256; }
    else if (bid < 512) { src = W_out; bsrc = b_out; col = bid - 256; nc = 256; }
    else                { src = W_hh;  bsrc = b_hh;  col = bid - 512; nc = 768; }
    Wt_all[bid * 256 + k] = f2bf(src[k * nc + col]);
    if (k == 0) b_all[bid] = bsrc[col];
  } else if (bid < 2048) {
    const int n = bid - 1280;
    WihT[n * 512 + k]       = f2bf(W_ih[k * 768 + n]);
    WihT[n * 512 + k + 256] = f2bf(W_ih[(k + 256) * 768 + n]);
  } else {
    const int n = bid - 2048;
    fc2T[n * 256 + k] = f2bf(fc2_w[k * 256 + n]);
  }
}

// ============ emb -> split bf16 hi/lo in TILED, XOR-SWIZZLED layout ============
// Layout: [t][p] tile of 16KB (t = v-tile of 64 rows, p = K-phase of 128 cols).
// Within a tile: byte X holds row = X>>8, unit w = (X>>4)&15; source col unit = w ^ (row&7).
// This makes global_load_lds staging a pure linear copy while ds_read applies the same XOR.
__global__ __launch_bounds__(256) void embsplit_t(const float* __restrict__ emb,
                                                  unsigned short* __restrict__ ehiT,
                                                  unsigned short* __restrict__ eloT)
{
  const int g = blockIdx.x * 256 + threadIdx.x;   // 16B-unit id
  const int u = g & 1023;
  const int tp = g >> 10;
  const int p = tp & 1, t = tp >> 1;
  const int row = u >> 4, w = u & 15;
  const int wp = w ^ (row & 7);
  const int v = t * 64 + row;
  float4 x0 = make_float4(0.f, 0.f, 0.f, 0.f), x1 = x0;
  if (v < VOC) {
    const float* s = &emb[(size_t)(v + 1) * HH + p * 128 + wp * 8];
    x0 = *(const float4*)s;
    x1 = *(const float4*)(s + 4);
  }
  uint2 l0, l1;
  const uint2 h0 = pack_hi4(x0, l0);
  const uint2 h1 = pack_hi4(x1, l1);
  uint4 H, L;
  H.x = h0.x; H.y = h0.y; H.z = h1.x; H.w = h1.y;
  L.x = l0.x; L.y = l0.y; L.z = l1.x; L.w = l1.y;
  *(uint4*)&ehiT[(size_t)g * 8] = H;
  *(uint4*)&eloT[(size_t)g * 8] = L;
}

// ============ A-split bf16 MFMA GEMM with global_load_lds staging ============
__global__ __launch_bounds__(256, 3) void gemm_asplit_nt(
    const unsigned short* __restrict__ Ah, const unsigned short* __restrict__ Al,
    const unsigned short* __restrict__ Bt, const float* __restrict__ bias,
    float* __restrict__ C, int N, int K, int ldc)
{
  __shared__ unsigned short sAh[4 * 128 * 8];
  __shared__ unsigned short sAl[4 * 128 * 8];
  __shared__ unsigned short sB [4 * 128 * 8];
  const int tid = threadIdx.x;
  const int n0 = blockIdx.x * 128, m0 = blockIdx.y * 128;
  const int lane = tid & 63, wave = tid >> 6;
  const int quad = lane >> 4, l16 = lane & 15;
  const int wm = (wave >> 1) * 64, wn = (wave & 1) * 64;

  f32x4 acc[4][4];
#pragma unroll
  for (int i = 0; i < 4; ++i)
#pragma unroll
    for (int j = 0; j < 4; ++j)
#pragma unroll
      for (int r = 0; r < 4; ++r) acc[i][j][r] = 0.f;

  const int c0 = tid, c1 = tid + 256;
  const int q0 = c0 >> 7, r0 = c0 & 127;
  const int q1c = c1 >> 7, r1 = c1 & 127;

  for (int k0 = 0; k0 < K; k0 += 32) {
    const size_t ga0 = (size_t)(m0 + r0) * K + k0 + q0 * 8;
    const size_t ga1 = (size_t)(m0 + r1) * K + k0 + q1c * 8;
    const size_t gb0 = (size_t)(n0 + r0) * K + k0 + q0 * 8;
    const size_t gb1 = (size_t)(n0 + r1) * K + k0 + q1c * 8;
    cp16(&sAh[c0 * 8], &Ah[ga0]);
    cp16(&sAh[c1 * 8], &Ah[ga1]);
    cp16(&sAl[c0 * 8], &Al[ga0]);
    cp16(&sAl[c1 * 8], &Al[ga1]);
    cp16(&sB [c0 * 8], &Bt[gb0]);
    cp16(&sB [c1 * 8], &Bt[gb1]);
    __syncthreads();

    short8 fah[4], fal[4];
#pragma unroll
    for (int ms = 0; ms < 4; ++ms) {
      const int row = wm + ms * 16 + l16;
      fah[ms] = *(const short8*)&sAh[(quad * 128 + row) * 8];
      fal[ms] = *(const short8*)&sAl[(quad * 128 + row) * 8];
    }
#pragma unroll
    for (int ns = 0; ns < 4; ++ns) {
      const int col = wn + ns * 16 + l16;
      const short8 fb = *(const short8*)&sB[(quad * 128 + col) * 8];
#pragma unroll
      for (int ms = 0; ms < 4; ++ms) {
        acc[ms][ns] = __builtin_amdgcn_mfma_f32_16x16x32_bf16(fah[ms], fb, acc[ms][ns], 0, 0, 0);
        acc[ms][ns] = __builtin_amdgcn_mfma_f32_16x16x32_bf16(fal[ms], fb, acc[ms][ns], 0, 0, 0);
      }
    }
    __syncthreads();
  }

#pragma unroll
  for (int ns = 0; ns < 4; ++ns) {
    const int n = n0 + wn + ns * 16 + l16;
    const float bv = bias[n];
#pragma unroll
    for (int ms = 0; ms < 4; ++ms) {
      const int mrow = m0 + wm + ms * 16 + quad * 4;
#pragma unroll
      for (int r = 0; r < 4; ++r)
        C[(size_t)(mrow + r) * ldc + n] = acc[ms][ns][r] + bv;
    }
  }
}

// ============ fp32 tiled GEMM kept for tiny q1 ============
#define TS 64
#define KSTEP 16
#define LDPF 68
__global__ __launch_bounds__(256) void gemm_nn_bias(
    const float* __restrict__ A, const float* __restrict__ W,
    const float* __restrict__ bias, float* __restrict__ C,
    int M, int N, int K)
{
  __shared__ float As[KSTEP * LDPF];
  __shared__ float Ws[KSTEP * LDPF];
  const int tid = threadIdx.x;
  const int tx = tid & 15, ty = tid >> 4;
  const int n0 = blockIdx.x * TS, m0 = blockIdx.y * TS;
  const int lkk = tid & 15, lm = tid >> 4;
  const int ln  = tid & 63, lkr = tid >> 6;
  float acc[4][4] = {};
  for (int k0 = 0; k0 < K; k0 += KSTEP) {
#pragma unroll
    for (int r = 0; r < 4; ++r)
      As[lkk * LDPF + lm + r * 16] = A[(m0 + lm + r * 16) * K + k0 + lkk];
#pragma unroll
    for (int r = 0; r < 4; ++r)
      Ws[(lkr + r * 4) * LDPF + ln] = W[(k0 + lkr + r * 4) * N + n0 + ln];
    __syncthreads();
#pragma unroll
    for (int kk = 0; kk < KSTEP; ++kk) {
      const float4 a4 = *(const float4*)(As + kk * LDPF + ty * 4);
      const float4 w4 = *(const float4*)(Ws + kk * LDPF + tx * 4);
      const float av[4] = {a4.x, a4.y, a4.z, a4.w};
      const float wv[4] = {w4.x, w4.y, w4.z, w4.w};
#pragma unroll
      for (int i = 0; i < 4; ++i)
#pragma unroll
        for (int j = 0; j < 4; ++j)
          acc[i][j] += av[i] * wv[j];
    }
    __syncthreads();
  }
  const float4 b4 = *(const float4*)(bias + n0 + tx * 4);
  const float bv[4] = {b4.x, b4.y, b4.z, b4.w};
#pragma unroll
  for (int i = 0; i < 4; ++i) {
    float4 o;
    o.x = acc[i][0] + bv[0]; o.y = acc[i][1] + bv[1];
    o.z = acc[i][2] + bv[2]; o.w = acc[i][3] + bv[3];
    *(float4*)(C + (m0 + ty * 4 + i) * N + n0 + tx * 4) = o;
  }
}

// ============ h0 = emb[items] (+ bf16 split) ============
__global__ void gather_h0(const int* __restrict__ items, const float* __restrict__ emb,
                          float* __restrict__ h0, unsigned short* __restrict__ h0h,
                          unsigned short* __restrict__ h0l, int total4)
{
  const int e = blockIdx.x * blockDim.x + threadIdx.x;
  if (e >= total4) return;
  const int row = e >> 6, c = e & 63;
  const int it = items[row];
  const float4 x = ((const float4*)emb)[it * 64 + c];
  ((float4*)h0)[e] = x;
  uint2 pl;
  const uint2 ph = pack_hi4(x, pl);
  *(uint2*)&h0h[e * 4] = ph;
  *(uint2*)&h0l[e * 4] = pl;
}

// ============ a_cat = [A_in@hin, A_out@hout] -> bf16 hi/lo ============
__global__ __launch_bounds__(256) void msg_kernel(
    const float* __restrict__ A, const float* __restrict__ C1,
    unsigned short* __restrict__ ach, unsigned short* __restrict__ acl)
{
  const int b = blockIdx.x;
  const int tid = threadIdx.x;
  __shared__ float Ash[NB * 64];
#pragma unroll
  for (int r = 0; r < 8; ++r)
    Ash[tid + r * 256] = A[b * (NB * 2 * NB) + tid + r * 256];
  float hi[NB], ho[NB];
#pragma unroll
  for (int j = 0; j < NB; ++j) {
    hi[j] = C1[(size_t)(b * NB + j) * 1280 + tid];
    ho[j] = C1[(size_t)(b * NB + j) * 1280 + 256 + tid];
  }
  __syncthreads();
  for (int i = 0; i < NB; ++i) {
    float si = 0.f, so = 0.f;
#pragma unroll
    for (int j = 0; j < NB; ++j) {
      si += Ash[i * 64 + j] * hi[j];
      so += Ash[i * 64 + 32 + j] * ho[j];
    }
    const int idx = (b * NB + i) * 512 + tid;
    const unsigned short sh = f2bf(si);
    ach[idx] = sh; acl[idx] = f2bf(si - bf2f(sh));
    const unsigned short oh = f2bf(so);
    ach[idx + 256] = oh; acl[idx + 256] = f2bf(so - bf2f(oh));
  }
}

// ============ GRU elementwise; h updated in place ============
__global__ void gru_kernel(const float* __restrict__ gi, const float* __restrict__ C1,
                           float* __restrict__ h, int total)
{
  const int idx = blockIdx.x * blockDim.x + threadIdx.x;
  if (idx >= total) return;
  const int row = idx >> 8, k = idx & 255;
  const float* gir = gi + (size_t)row * 768;
  const float* ghr = C1 + (size_t)row * 1280 + 512;
  const float ir = gir[k], iz = gir[k + 256], inn = gir[k + 512];
  const float hr = ghr[k], hz = ghr[k + 256], hn = ghr[k + 512];
  const float r = 1.f / (1.f + expf(-(ir + hr)));
  const float z = 1.f / (1.f + expf(-(iz + hz)));
  const float n = tanhf(inn + r * hn);
  const float h0v = h[idx];
  h[idx] = n + z * (h0v - n);
}

// ============ h_seqs gather (+ split) + tail; L split across gridDim.y ============
__global__ __launch_bounds__(256) void seq_gather2(
    const int* __restrict__ seq_alias, const int* __restrict__ mask,
    const float* __restrict__ h, float* __restrict__ h_seqs,
    unsigned short* __restrict__ hsh, unsigned short* __restrict__ hsl,
    float* __restrict__ h_tail)
{
  const int b = blockIdx.x, tid = threadIdx.x;
  __shared__ int tail_sh;
  if (tid < 64) {
    int s = (tid < LSEQ) ? mask[b * LSEQ + tid] : 0;
#pragma unroll
    for (int off = 32; off > 0; off >>= 1) s += __shfl_down(s, off, 64);
    if (tid == 0) tail_sh = s - 1;
  }
  __syncthreads();
  const int tail = tail_sh;
  const int l0 = blockIdx.y * 10;
  for (int l = l0; l < l0 + 10; ++l) {
    const int al = seq_alias[b * LSEQ + l];
    const float v = h[(size_t)(b * NB + al) * HH + tid];
    const int idx = (b * LSEQ + l) * HH + tid;
    h_seqs[idx] = v;
    const unsigned short vh = f2bf(v);
    hsh[idx] = vh; hsl[idx] = f2bf(v - bf2f(vh));
    if (l == tail) h_tail[b * HH + tid] = v;
  }
}

// ============ attention pooling: wave-parallel over L, one barrier ============
__global__ __launch_bounds__(256) void attn_kernel2(
    const float* __restrict__ q1, const float* __restrict__ q2,
    const float* __restrict__ fc3_w, const float* __restrict__ h_seqs,
    const int* __restrict__ mask, float* __restrict__ seq_emb)
{
  const int b = blockIdx.x;
  const int tid = threadIdx.x, wave = tid >> 6, lane = tid & 63;
  __shared__ float red[4 * HH];
  const float4 q1v = *(const float4*)&q1[b * HH + lane * 4];
  const float4 w3v = *(const float4*)&fc3_w[lane * 4];
  float4 acc = make_float4(0.f, 0.f, 0.f, 0.f);
  for (int l = wave; l < LSEQ; l += 4) {
    if (!mask[b * LSEQ + l]) continue;
    const float4 q2v = *(const float4*)&q2[(size_t)(b * LSEQ + l) * HH + lane * 4];
    float s = (1.f / (1.f + expf(-(q1v.x + q2v.x)))) * w3v.x
            + (1.f / (1.f + expf(-(q1v.y + q2v.y)))) * w3v.y
            + (1.f / (1.f + expf(-(q1v.z + q2v.z)))) * w3v.z
            + (1.f / (1.f + expf(-(q1v.w + q2v.w)))) * w3v.w;
#pragma unroll
    for (int off = 32; off > 0; off >>= 1) s += __shfl_xor(s, off, 64);
    const float4 hv = *(const float4*)&h_seqs[(size_t)(b * LSEQ + l) * HH + lane * 4];
    acc.x += s * hv.x; acc.y += s * hv.y; acc.z += s * hv.z; acc.w += s * hv.w;
  }
  *(float4*)&red[wave * HH + lane * 4] = acc;
  __syncthreads();
  const float r = red[tid] + red[HH + tid] + red[2 * HH + tid] + red[3 * HH + tid];
  seq_emb[b * HH + tid] = r;
}

// ============ split seq_emb ============
__global__ void split_seq(const float* __restrict__ s, unsigned short* __restrict__ hi,
                          unsigned short* __restrict__ lo, int n)
{
  const int i = blockIdx.x * blockDim.x + threadIdx.x;
  if (i >= n) return;
  const float x = s[i];
  const unsigned short h = f2bf(x);
  hi[i] = h;
  lo[i] = f2bf(x - bf2f(h));
}

// ============ scorer v3: presplit tiles + async LDS staging + XOR-swizzled reads ============
// grid (NTILE v-tiles, 2 m-blocks) — v-major dispatch restores the L3 merge of the
// second m-pass (FETCH = emb once). Double-buffered 2-phase K loop.
__global__ __launch_bounds__(256, 2) void scorer_split_lds(
    const unsigned short* __restrict__ seq_hi,
    const unsigned short* __restrict__ seq_lo,
    const unsigned short* __restrict__ ehiT,
    const unsigned short* __restrict__ eloT,
    float* __restrict__ out)
{
  __shared__ unsigned short sH[2][8192];   // [buf][64 rows x 128 cols] swizzled
  __shared__ unsigned short sL[2][8192];
  const int tid = threadIdx.x;
  const int t = blockIdx.x;            // v-tile
  const int m0 = blockIdx.y * 256;
  const int lane = tid & 63, wave = tid >> 6;
  const int quad = lane >> 4, l16 = lane & 15;
  const int mwave = m0 + wave * 64;

  f32x4 acc[4][4];
#pragma unroll
  for (int i = 0; i < 4; ++i)
#pragma unroll
    for (int j = 0; j < 4; ++j)
#pragma unroll
      for (int r = 0; r < 4; ++r) acc[i][j][r] = 0.f;

  const size_t tb = (size_t)t * 16384;   // us offset of tile t (2 phases x 8192 us)

  // stage phase 0 -> buf 0 (linear copy; source is pre-swizzled)
#pragma unroll
  for (int j = 0; j < 4; ++j) {
    const int o = (tid + j * 256) * 8;
    cp16(&sH[0][o], &ehiT[tb + o]);
    cp16(&sL[0][o], &eloT[tb + o]);
  }
  __syncthreads();   // compiler drains vmcnt before barrier

  // stage phase 1 -> buf 1 (async; overlaps compute of phase 0)
#pragma unroll
  for (int j = 0; j < 4; ++j) {
    const int o = (tid + j * 256) * 8;
    cp16(&sH[1][o], &ehiT[tb + 8192 + o]);
    cp16(&sL[1][o], &eloT[tb + 8192 + o]);
  }

#define SCORE_PHASE(D, P)                                                          \
  {                                                                                \
    _Pragma("unroll")                                                              \
    for (int ks = 0; ks < 4; ++ks) {                                               \
      const int kk = ks * 32;                                                      \
      short8 bh[4], bl[4];                                                         \
      _Pragma("unroll")                                                            \
      for (int vs = 0; vs < 4; ++vs) {                                             \
        const int row = vs * 16 + l16;                                             \
        const int bo = (row * 256 + (kk + quad * 8) * 2) ^ ((row & 7) << 4);       \
        bh[vs] = *(const short8*)((const char*)&sH[D][0] + bo);                    \
        bl[vs] = *(const short8*)((const char*)&sL[D][0] + bo);                    \
      }                                                                            \
      _Pragma("unroll")                                                            \
      for (int ms = 0; ms < 4; ++ms) {                                             \
        const int aoff = (mwave + ms * 16 + l16) * HH + (P) * 128 + kk + quad * 8; \
        const short8 ah = *(const short8*)&seq_hi[aoff];                           \
        const short8 al = *(const short8*)&seq_lo[aoff];                           \
        _Pragma("unroll")                                                          \
        for (int vs = 0; vs < 4; ++vs) {                                           \
          acc[ms][vs] = __builtin_amdgcn_mfma_f32_16x16x32_bf16(ah, bh[vs], acc[ms][vs], 0, 0, 0); \
          acc[ms][vs] = __builtin_amdgcn_mfma_f32_16x16x32_bf16(ah, bl[vs], acc[ms][vs], 0, 0, 0); \
          acc[ms][vs] = __builtin_amdgcn_mfma_f32_16x16x32_bf16(al, bh[vs], acc[ms][vs], 0, 0, 0); \
        }                                                                          \
      }                                                                            \
    }                                                                              \
  }

  SCORE_PHASE(0, 0)
  __syncthreads();   // drains vmcnt(0): buf1 staged; buf0 reads done
  SCORE_PHASE(1, 1)

  const int v0 = t * 64;
#pragma unroll
  for (int ms = 0; ms < 4; ++ms) {
    const int mrow = mwave + ms * 16 + quad * 4;
#pragma unroll
    for (int vs = 0; vs < 4; ++vs) {
      const int v = v0 + vs * 16 + l16;
      if (v < VOC) {
#pragma unroll
        for (int r = 0; r < 4; ++r)
          out[(size_t)(mrow + r) * VOC + v] = acc[ms][vs][r];
      }
    }
  }
#undef SCORE_PHASE
}

// ============ scorer fallback (in-kernel conversion) ============
#define ELD2 136
__global__ __launch_bounds__(256, 3) void scorer_mfma(
    const unsigned short* __restrict__ seq_hi,
    const unsigned short* __restrict__ seq_lo,
    const float* __restrict__ emb,
    float* __restrict__ out)
{
  __shared__ unsigned short ehi[64 * ELD2];
  __shared__ unsigned short elo[64 * ELD2];
  const int tid = threadIdx.x;
  const int v0 = blockIdx.x * 64;
  const int m0 = blockIdx.y * 256;
  const int lane = tid & 63, wave = tid >> 6;
  const int quad = lane >> 4, l16 = lane & 15;
  const int mwave = m0 + wave * 64;

  f32x4 acc[4][4];
#pragma unroll
  for (int i = 0; i < 4; ++i)
#pragma unroll
    for (int j = 0; j < 4; ++j)
#pragma unroll
      for (int r = 0; r < 4; ++r) acc[i][j][r] = 0.f;

  for (int p = 0; p < 2; ++p) {
#pragma unroll
    for (int i = 0; i < 8; ++i) {
      const int idx4 = tid + i * 256;
      const int row = idx4 >> 5, c4 = idx4 & 31;
      const int v = v0 + row;
      float4 x = make_float4(0.f, 0.f, 0.f, 0.f);
      if (v < VOC) x = *(const float4*)&emb[(size_t)(v + 1) * HH + p * 128 + c4 * 4];
      uint2 pl;
      const uint2 ph = pack_hi4(x, pl);
      *(uint2*)&ehi[row * ELD2 + c4 * 4] = ph;
      *(uint2*)&elo[row * ELD2 + c4 * 4] = pl;
    }
    __syncthreads();

#pragma unroll
    for (int ks = 0; ks < 4; ++ks) {
      const int kk = ks * 32;
      short8 bh[4], bl[4];
#pragma unroll
      for (int vs = 0; vs < 4; ++vs) {
        const int off = (vs * 16 + l16) * ELD2 + kk + quad * 8;
        bh[vs] = *(const short8*)&ehi[off];
        bl[vs] = *(const short8*)&elo[off];
      }
#pragma unroll
      for (int ms = 0; ms < 4; ++ms) {
        const int m = mwave + ms * 16 + l16;
        const int aoff = m * HH + p * 128 + kk + quad * 8;
        const short8 ah = *(const short8*)&seq_hi[aoff];
        const short8 al = *(const short8*)&seq_lo[aoff];
#pragma unroll
        for (int vs = 0; vs < 4; ++vs) {
          acc[ms][vs] = __builtin_amdgcn_mfma_f32_16x16x32_bf16(ah, bh[vs], acc[ms][vs], 0, 0, 0);
          acc[ms][vs] = __builtin_amdgcn_mfma_f32_16x16x32_bf16(ah, bl[vs], acc[ms][vs], 0, 0, 0);
          acc[ms][vs] = __builtin_amdgcn_mfma_f32_16x16x32_bf16(al, bh[vs], acc[ms][vs], 0, 0, 0);
        }
      }
    }
    __syncthreads();
  }

#pragma unroll
  for (int ms = 0; ms < 4; ++ms) {
    const int mrow = mwave + ms * 16 + quad * 4;
#pragma unroll
    for (int vs = 0; vs < 4; ++vs) {
      const int v = v0 + vs * 16 + l16;
      if (v < VOC) {
#pragma unroll
        for (int r = 0; r < 4; ++r)
          out[(size_t)(mrow + r) * VOC + v] = acc[ms][vs][r];
      }
    }
  }
}

extern "C" void kernel_launch(void* const* d_in, const int* in_sizes, int n_in,
                              void* d_out, int out_size, void* d_ws, size_t ws_size,
                              hipStream_t stream)
{
  const float* A      = (const float*)d_in[0];
  const int* items    = (const int*)d_in[1];
  const int* seq_al   = (const int*)d_in[2];
  const int* mask     = (const int*)d_in[3];
  const float* emb    = (const float*)d_in[4];
  const float* W_in   = (const float*)d_in[5];
  const float* b_in   = (const float*)d_in[6];
  const float* W_out  = (const float*)d_in[7];
  const float* b_out  = (const float*)d_in[8];
  const float* W_ih   = (const float*)d_in[9];
  const float* b_ih   = (const float*)d_in[10];
  const float* b_hh   = (const float*)d_in[12];
  const float* W_hh   = (const float*)d_in[11];
  const float* fc1_w  = (const float*)d_in[13];
  const float* fc1_b  = (const float*)d_in[14];
  const float* fc2_w  = (const float*)d_in[15];
  const float* fc2_b  = (const float*)d_in[16];
  const float* fc3_w  = (const float*)d_in[17];
  float* out = (float*)d_out;

  // ---- ws layout (floats) ----
  float* ws = (float*)d_ws;
  float* h0      = ws;                  // 4,194,304
  float* q1      = ws + 4194304;
  float* h_tail  = ws + 4325376;
  float* seq_emb = ws + 4456448;
  unsigned short* seq_hi = (unsigned short*)(ws + 4587520);
  unsigned short* seq_lo = (unsigned short*)(ws + 4653056);
  unsigned short* Wt_all = (unsigned short*)(ws + 4718592);
  unsigned short* WihT   = (unsigned short*)(ws + 4882432);
  unsigned short* fc2T   = (unsigned short*)(ws + 5079040);
  float* b_all   = ws + 5111808;        // 1,280
  // pre-split tiled emb (VPAD x 256 us each) at 5,113,088 floats
  unsigned short* emb_hiT = (unsigned short*)(ws + 5113088);
  unsigned short* emb_loT = (unsigned short*)(ws + 5113088 + (size_t)VPAD * HH / 2);
  const bool presplit = ws_size >= ((size_t)5113088 * 4 + (size_t)VPAD * HH * 4);

  // ---- d_out scratch ----
  float* C1 = out;
  unsigned short* acat_h = (unsigned short*)(out + 20971520);
  unsigned short* acat_l = (unsigned short*)(out + 25165824);
  float* gi = out + 29360128;
  unsigned short* h0h = (unsigned short*)(out + 41943040);
  unsigned short* h0l = (unsigned short*)(out + 44040192);
  float* h_seqs = out;
  unsigned short* hs_h = (unsigned short*)(out + 6553600);
  unsigned short* hs_l = (unsigned short*)(out + 9830400);
  float* q2 = out + 13107200;

  const int MR = BB * NB;  // 16384

  prep_weights<<<dim3(2304), dim3(256), 0, stream>>>(
      W_in, b_in, W_out, b_out, W_hh, b_hh, W_ih, fc2_w, Wt_all, b_all, WihT, fc2T);

  if (presplit)
    embsplit_t<<<dim3(NTILE * 8), dim3(256), 0, stream>>>(emb, emb_hiT, emb_loT);

  gather_h0<<<dim3(MR * 64 / 256), dim3(256), 0, stream>>>(items, emb, h0, h0h, h0l, MR * 64);

  gemm_asplit_nt<<<dim3(1280 / 128, MR / 128), dim3(256), 0, stream>>>(
      h0h, h0l, Wt_all, b_all, C1, 1280, 256, 1280);

  msg_kernel<<<dim3(BB), dim3(256), 0, stream>>>(A, C1, acat_h, acat_l);

  gemm_asplit_nt<<<dim3(768 / 128, MR / 128), dim3(256), 0, stream>>>(
      acat_h, acat_l, WihT, b_ih, gi, 768, 512, 768);

  gru_kernel<<<dim3(MR * HH / 256), dim3(256), 0, stream>>>(gi, C1, h0, MR * HH);

  seq_gather2<<<dim3(BB, 5), dim3(256), 0, stream>>>(seq_al, mask, h0, h_seqs, hs_h, hs_l, h_tail);

  gemm_asplit_nt<<<dim3(256 / 128, (BB * LSEQ) / 128), dim3(256), 0, stream>>>(
      hs_h, hs_l, fc2T, fc2_b, q2, 256, 256, 256);

  gemm_nn_bias<<<dim3(HH / TS, BB / TS), dim3(256), 0, stream>>>(h_tail, fc1_w, fc1_b, q1, BB, HH, HH);

  attn_kernel2<<<dim3(BB), dim3(256), 0, stream>>>(q1, q2, fc3_w, h_seqs, mask, seq_emb);

  split_seq<<<dim3(BB * HH / 256), dim3(256), 0, stream>>>(seq_emb, seq_hi, seq_lo, BB * HH);

  if (presplit)
    scorer_split_lds<<<dim3(NTILE, 2), dim3(256), 0, stream>>>(
        seq_hi, seq_lo, emb_hiT, emb_loT, out);
  else
    scorer_mfma<<<dim3((VOC + 63) / 64, 2), dim3(256), 0, stream>>>(seq_hi, seq_lo, emb, out);
}